// Round 1
// baseline (5683.234 us; speedup 1.0000x reference)
//
#include <hip/hip_runtime.h>
#include <math.h>

// 2-layer LSTM (B=1024,T=512,F=64,H=128) + FC head, fp32.
// Structure: persistent per-batch-tile recurrence kernels (no grid sync needed:
// batches independent), weights register-resident (thread j owns gate-column j),
// h exchanged via LDS [k][m] so ds_read_b128 broadcast feeds 4 FMAs.
// Layer1 in-proj materialized as chunked parallel GEMM (ws-size adaptive).

#define BB 1024
#define TT 512
#define FF 64
#define HH 128
#define GG 512  // 4*H

__device__ __forceinline__ float sigmoidf_(float x) {
    return 1.0f / (1.0f + __expf(-x));
}

// ---------------- Layer 0: fused in-proj + recurrence -----------------
// grid 256 blocks x 512 threads; block owns 4 batch rows; thread j owns column j.
__global__ __launch_bounds__(512) void lstm0_kernel(
    const float* __restrict__ x, const float* __restrict__ Wih,
    const float* __restrict__ Whh, const float* __restrict__ bih,
    const float* __restrict__ bhh, float* __restrict__ h1)
{
    const int tid = threadIdx.x;
    const int blk = blockIdx.x;
    const int j = tid;

    float wih[FF];
    float whh[HH];
#pragma unroll
    for (int q = 0; q < FF / 4; ++q)
        *(float4*)&wih[4 * q] = *(const float4*)&Wih[j * FF + 4 * q];
#pragma unroll
    for (int q = 0; q < HH / 4; ++q)
        *(float4*)&whh[4 * q] = *(const float4*)&Whh[j * HH + 4 * q];
    const float bsum = bih[j] + bhh[j];

    __shared__ __align__(16) float h_lds[HH * 4];   // [k][m]
    __shared__ __align__(16) float x_lds[FF * 4];   // [k][m]
    __shared__ __align__(16) float pre_lds[4 * GG]; // [m][j]

    h_lds[tid] = 0.0f;  // exactly 512 entries
    const int um = tid >> 7;     // update row 0..3
    const int uj = tid & 127;    // update h-index
    float c = 0.0f;
    const long b0 = (long)blk * 4;

    for (int t = 0; t < TT; ++t) {
        if (tid < 256) {
            int k = tid & 63, m = tid >> 6;
            x_lds[k * 4 + m] = x[((b0 + m) * TT + t) * FF + k];
        }
        __syncthreads();  // x staged; h_lds writes from prev step visible

        float a0 = bsum, a1 = bsum, a2 = bsum, a3 = bsum;
#pragma unroll
        for (int k = 0; k < FF; ++k) {
            float4 v = *(const float4*)&x_lds[k * 4];
            a0 = fmaf(v.x, wih[k], a0);
            a1 = fmaf(v.y, wih[k], a1);
            a2 = fmaf(v.z, wih[k], a2);
            a3 = fmaf(v.w, wih[k], a3);
        }
#pragma unroll
        for (int k = 0; k < HH; ++k) {
            float4 v = *(const float4*)&h_lds[k * 4];
            a0 = fmaf(v.x, whh[k], a0);
            a1 = fmaf(v.y, whh[k], a1);
            a2 = fmaf(v.z, whh[k], a2);
            a3 = fmaf(v.w, whh[k], a3);
        }
        pre_lds[0 * GG + j] = a0;
        pre_lds[1 * GG + j] = a1;
        pre_lds[2 * GG + j] = a2;
        pre_lds[3 * GG + j] = a3;
        __syncthreads();

        float pi = pre_lds[um * GG + uj];
        float pf = pre_lds[um * GG + 128 + uj];
        float pg = pre_lds[um * GG + 256 + uj];
        float po = pre_lds[um * GG + 384 + uj];
        float ig = sigmoidf_(pi);
        float fg = sigmoidf_(pf);
        float gg = tanhf(pg);
        float og = sigmoidf_(po);
        c = fmaf(fg, c, ig * gg);
        float h = og * tanhf(c);
        h_lds[uj * 4 + um] = h;                       // next step's GEMM input
        h1[((b0 + um) * TT + t) * HH + uj] = h;       // coalesced per row
    }
}

// ---------------- xp1 = h1 @ W_ih1^T + (b_ih1+b_hh1), chunked over T ---------
// grid 256 x 512; thread j holds W_ih1 row j (128 regs); 8-row LDS tiles.
__global__ __launch_bounds__(512) void xp1_gemm_kernel(
    const float* __restrict__ h1, const float* __restrict__ Wih,
    const float* __restrict__ bih, const float* __restrict__ bhh,
    float* __restrict__ xp, int t0, int TC)
{
    const int tid = threadIdx.x;
    const int blk = blockIdx.x;
    const int j = tid;

    float w[HH];
#pragma unroll
    for (int q = 0; q < HH / 4; ++q)
        *(float4*)&w[4 * q] = *(const float4*)&Wih[j * HH + 4 * q];
    const float bsum = bih[j] + bhh[j];

    __shared__ __align__(16) float hl[HH * 8];  // [k][m]

    const int rpb = (BB * TC) / 256;  // rows per block, multiple of 8 for TC>=2
    const long r0b = (long)blk * rpb;

    for (int tile = 0; tile < rpb / 8; ++tile) {
        const long r0 = r0b + tile * 8;
        __syncthreads();  // protect hl against previous tile's readers
#pragma unroll
        for (int p = 0; p < 2; ++p) {
            int e = tid + p * 512;
            int k = e & 127, m = e >> 7;   // coalesced over k
            long r = r0 + m;
            long b = r / TC, tloc = r % TC;
            hl[k * 8 + m] = h1[(b * TT + t0 + tloc) * HH + k];
        }
        __syncthreads();

        float acc[8];
#pragma unroll
        for (int m = 0; m < 8; ++m) acc[m] = bsum;
#pragma unroll
        for (int k = 0; k < HH; ++k) {
            float4 v0 = *(const float4*)&hl[k * 8];
            float4 v1 = *(const float4*)&hl[k * 8 + 4];
            acc[0] = fmaf(v0.x, w[k], acc[0]);
            acc[1] = fmaf(v0.y, w[k], acc[1]);
            acc[2] = fmaf(v0.z, w[k], acc[2]);
            acc[3] = fmaf(v0.w, w[k], acc[3]);
            acc[4] = fmaf(v1.x, w[k], acc[4]);
            acc[5] = fmaf(v1.y, w[k], acc[5]);
            acc[6] = fmaf(v1.z, w[k], acc[6]);
            acc[7] = fmaf(v1.w, w[k], acc[7]);
        }
#pragma unroll
        for (int m = 0; m < 8; ++m)
            xp[(r0 + m) * GG + j] = acc[m];
    }
}

// ---------------- Layer 1 recurrence over one T-chunk ----------------------
__global__ __launch_bounds__(512) void lstm1_kernel(
    const float* __restrict__ xp, const float* __restrict__ Whh,
    float* __restrict__ h_state, float* __restrict__ c_state, int TC)
{
    const int tid = threadIdx.x;
    const int blk = blockIdx.x;
    const int j = tid;

    float whh[HH];
#pragma unroll
    for (int q = 0; q < HH / 4; ++q)
        *(float4*)&whh[4 * q] = *(const float4*)&Whh[j * HH + 4 * q];

    __shared__ __align__(16) float h_lds[HH * 4];
    __shared__ __align__(16) float pre_lds[4 * GG];

    const int um = tid >> 7;
    const int uj = tid & 127;
    const long b0 = (long)blk * 4;

    float c = c_state[(b0 + um) * HH + uj];
    h_lds[tid] = h_state[(b0 + (tid & 3)) * HH + (tid >> 2)];

    for (int tt = 0; tt < TC; ++tt) {
        __syncthreads();  // h_lds (init or prev update) visible

        float a0 = xp[((b0 + 0) * TC + tt) * GG + j];
        float a1 = xp[((b0 + 1) * TC + tt) * GG + j];
        float a2 = xp[((b0 + 2) * TC + tt) * GG + j];
        float a3 = xp[((b0 + 3) * TC + tt) * GG + j];
#pragma unroll
        for (int k = 0; k < HH; ++k) {
            float4 v = *(const float4*)&h_lds[k * 4];
            a0 = fmaf(v.x, whh[k], a0);
            a1 = fmaf(v.y, whh[k], a1);
            a2 = fmaf(v.z, whh[k], a2);
            a3 = fmaf(v.w, whh[k], a3);
        }
        pre_lds[0 * GG + j] = a0;
        pre_lds[1 * GG + j] = a1;
        pre_lds[2 * GG + j] = a2;
        pre_lds[3 * GG + j] = a3;
        __syncthreads();

        float pi = pre_lds[um * GG + uj];
        float pf = pre_lds[um * GG + 128 + uj];
        float pg = pre_lds[um * GG + 256 + uj];
        float po = pre_lds[um * GG + 384 + uj];
        float ig = sigmoidf_(pi);
        float fg = sigmoidf_(pf);
        float gg = tanhf(pg);
        float og = sigmoidf_(po);
        c = fmaf(fg, c, ig * gg);
        float h = og * tanhf(c);
        h_lds[uj * 4 + um] = h;
    }
    __syncthreads();
    c_state[(b0 + um) * HH + uj] = c;
    h_state[(b0 + (tid & 3)) * HH + (tid >> 2)] = h_lds[tid];
}

// ---------------- FC head: out = relu(h @ fc1^T + b1) @ fc2^T + b2 ---------
__global__ __launch_bounds__(64) void head_kernel(
    const float* __restrict__ h, const float* __restrict__ w1,
    const float* __restrict__ b1, const float* __restrict__ w2,
    const float* __restrict__ b2, float* __restrict__ out)
{
    const int b = blockIdx.x;
    const int n = threadIdx.x;
    float acc = b1[n];
#pragma unroll
    for (int k = 0; k < HH; ++k)
        acc = fmaf(w1[n * HH + k], h[b * HH + k], acc);
    float v = fmaxf(acc, 0.0f) * w2[n];
#pragma unroll
    for (int off = 32; off > 0; off >>= 1)
        v += __shfl_down(v, off);
    if (n == 0) out[b] = v + b2[0];
}

extern "C" void kernel_launch(void* const* d_in, const int* in_sizes, int n_in,
                              void* d_out, int out_size, void* d_ws, size_t ws_size,
                              hipStream_t stream)
{
    const float* x    = (const float*)d_in[0];
    const float* Wih0 = (const float*)d_in[1];
    const float* Whh0 = (const float*)d_in[2];
    const float* bih0 = (const float*)d_in[3];
    const float* bhh0 = (const float*)d_in[4];
    const float* Wih1 = (const float*)d_in[5];
    const float* Whh1 = (const float*)d_in[6];
    const float* bih1 = (const float*)d_in[7];
    const float* bhh1 = (const float*)d_in[8];
    const float* w1   = (const float*)d_in[9];
    const float* b1   = (const float*)d_in[10];
    const float* w2   = (const float*)d_in[11];
    const float* b2   = (const float*)d_in[12];
    float* out = (float*)d_out;

    char* ws = (char*)d_ws;
    const size_t sz_h1 = (size_t)BB * TT * HH * 4;       // 268 MB
    const size_t sz_state = (size_t)BB * HH * 4;         // 512 KB each

    // pick largest T-chunk that fits the workspace
    int TC = 2;
    const int cands[6] = {64, 32, 16, 8, 4, 2};
    for (int i = 0; i < 6; ++i) {
        size_t need = sz_h1 + (size_t)BB * cands[i] * GG * 4 + 2 * sz_state;
        if (need <= ws_size) { TC = cands[i]; break; }
    }

    float* h1 = (float*)(ws);
    float* xp = (float*)(ws + sz_h1);
    float* hs = (float*)(ws + sz_h1 + (size_t)BB * TC * GG * 4);
    float* cs = hs + (size_t)BB * HH;

    hipMemsetAsync(hs, 0, 2 * sz_state, stream);

    lstm0_kernel<<<256, 512, 0, stream>>>(x, Wih0, Whh0, bih0, bhh0, h1);
    for (int t0 = 0; t0 < TT; t0 += TC) {
        xp1_gemm_kernel<<<256, 512, 0, stream>>>(h1, Wih1, bih1, bhh1, xp, t0, TC);
        lstm1_kernel<<<256, 512, 0, stream>>>(xp, Whh1, hs, cs, TC);
    }
    head_kernel<<<BB, 64, 0, stream>>>(hs, w1, b1, w2, b2, out);
}

// Round 2
// 5356.108 us; speedup vs baseline: 1.0611x; 1.0611x over previous
//
#include <hip/hip_runtime.h>
#include <math.h>

// 2-layer LSTM (B=1024,T=512,F=64,H=128) + FC head, fp32.
// R2 change: __launch_bounds__(512, 2) on all heavy kernels so the 192/128
// float weight arrays stay in VGPRs (R1 had VGPR_Count=116 < 192 declared
// weights -> AGPR/scratch spill, 58% of VALU cycles were spill traffic).
// Also fast tanh via __expf.

#define BB 1024
#define TT 512
#define FF 64
#define HH 128
#define GG 512  // 4*H

__device__ __forceinline__ float sigmoidf_(float x) {
    return 1.0f / (1.0f + __expf(-x));
}
__device__ __forceinline__ float tanhf_(float x) {
    // tanh(x) = 1 - 2/(1+exp(2x)); accurate to ~1e-7 rel in fp32 range
    return 1.0f - 2.0f / (1.0f + __expf(2.0f * x));
}

// ---------------- Layer 0: fused in-proj + recurrence -----------------
// grid 256 blocks x 512 threads; block owns 4 batch rows; thread j owns column j.
__global__ __launch_bounds__(512, 2) void lstm0_kernel(
    const float* __restrict__ x, const float* __restrict__ Wih,
    const float* __restrict__ Whh, const float* __restrict__ bih,
    const float* __restrict__ bhh, float* __restrict__ h1)
{
    const int tid = threadIdx.x;
    const int blk = blockIdx.x;
    const int j = tid;

    float wih[FF];
    float whh[HH];
#pragma unroll
    for (int q = 0; q < FF / 4; ++q)
        *(float4*)&wih[4 * q] = *(const float4*)&Wih[j * FF + 4 * q];
#pragma unroll
    for (int q = 0; q < HH / 4; ++q)
        *(float4*)&whh[4 * q] = *(const float4*)&Whh[j * HH + 4 * q];
    const float bsum = bih[j] + bhh[j];

    __shared__ __align__(16) float h_lds[HH * 4];   // [k][m]
    __shared__ __align__(16) float x_lds[FF * 4];   // [k][m]
    __shared__ __align__(16) float pre_lds[4 * GG]; // [m][j]

    h_lds[tid] = 0.0f;  // exactly 512 entries
    const int um = tid >> 7;     // update row 0..3
    const int uj = tid & 127;    // update h-index
    float c = 0.0f;
    const long b0 = (long)blk * 4;

    for (int t = 0; t < TT; ++t) {
        if (tid < 256) {
            int k = tid & 63, m = tid >> 6;
            x_lds[k * 4 + m] = x[((b0 + m) * TT + t) * FF + k];
        }
        __syncthreads();  // x staged; h_lds writes from prev step visible

        float a0 = bsum, a1 = bsum, a2 = bsum, a3 = bsum;
#pragma unroll
        for (int k = 0; k < FF; ++k) {
            float4 v = *(const float4*)&x_lds[k * 4];
            a0 = fmaf(v.x, wih[k], a0);
            a1 = fmaf(v.y, wih[k], a1);
            a2 = fmaf(v.z, wih[k], a2);
            a3 = fmaf(v.w, wih[k], a3);
        }
#pragma unroll
        for (int k = 0; k < HH; ++k) {
            float4 v = *(const float4*)&h_lds[k * 4];
            a0 = fmaf(v.x, whh[k], a0);
            a1 = fmaf(v.y, whh[k], a1);
            a2 = fmaf(v.z, whh[k], a2);
            a3 = fmaf(v.w, whh[k], a3);
        }
        pre_lds[0 * GG + j] = a0;
        pre_lds[1 * GG + j] = a1;
        pre_lds[2 * GG + j] = a2;
        pre_lds[3 * GG + j] = a3;
        __syncthreads();

        float pi = pre_lds[um * GG + uj];
        float pf = pre_lds[um * GG + 128 + uj];
        float pg = pre_lds[um * GG + 256 + uj];
        float po = pre_lds[um * GG + 384 + uj];
        float ig = sigmoidf_(pi);
        float fg = sigmoidf_(pf);
        float gg = tanhf_(pg);
        float og = sigmoidf_(po);
        c = fmaf(fg, c, ig * gg);
        float h = og * tanhf_(c);
        h_lds[uj * 4 + um] = h;                       // next step's GEMM input
        h1[((b0 + um) * TT + t) * HH + uj] = h;       // coalesced per row
    }
}

// ---------------- xp1 = h1 @ W_ih1^T + (b_ih1+b_hh1), chunked over T ---------
// grid 256 x 512; thread j holds W_ih1 row j (128 regs); 8-row LDS tiles.
__global__ __launch_bounds__(512, 2) void xp1_gemm_kernel(
    const float* __restrict__ h1, const float* __restrict__ Wih,
    const float* __restrict__ bih, const float* __restrict__ bhh,
    float* __restrict__ xp, int t0, int TC)
{
    const int tid = threadIdx.x;
    const int blk = blockIdx.x;
    const int j = tid;

    float w[HH];
#pragma unroll
    for (int q = 0; q < HH / 4; ++q)
        *(float4*)&w[4 * q] = *(const float4*)&Wih[j * HH + 4 * q];
    const float bsum = bih[j] + bhh[j];

    __shared__ __align__(16) float hl[HH * 8];  // [k][m]

    const int rpb = (BB * TC) / 256;  // rows per block, multiple of 8 for TC>=2
    const long r0b = (long)blk * rpb;

    for (int tile = 0; tile < rpb / 8; ++tile) {
        const long r0 = r0b + tile * 8;
        __syncthreads();  // protect hl against previous tile's readers
#pragma unroll
        for (int p = 0; p < 2; ++p) {
            int e = tid + p * 512;
            int k = e & 127, m = e >> 7;   // coalesced over k
            long r = r0 + m;
            long b = r / TC, tloc = r % TC;
            hl[k * 8 + m] = h1[(b * TT + t0 + tloc) * HH + k];
        }
        __syncthreads();

        float acc[8];
#pragma unroll
        for (int m = 0; m < 8; ++m) acc[m] = bsum;
#pragma unroll
        for (int k = 0; k < HH; ++k) {
            float4 v0 = *(const float4*)&hl[k * 8];
            float4 v1 = *(const float4*)&hl[k * 8 + 4];
            acc[0] = fmaf(v0.x, w[k], acc[0]);
            acc[1] = fmaf(v0.y, w[k], acc[1]);
            acc[2] = fmaf(v0.z, w[k], acc[2]);
            acc[3] = fmaf(v0.w, w[k], acc[3]);
            acc[4] = fmaf(v1.x, w[k], acc[4]);
            acc[5] = fmaf(v1.y, w[k], acc[5]);
            acc[6] = fmaf(v1.z, w[k], acc[6]);
            acc[7] = fmaf(v1.w, w[k], acc[7]);
        }
#pragma unroll
        for (int m = 0; m < 8; ++m)
            xp[(r0 + m) * GG + j] = acc[m];
    }
}

// ---------------- Layer 1 recurrence over one T-chunk ----------------------
__global__ __launch_bounds__(512, 2) void lstm1_kernel(
    const float* __restrict__ xp, const float* __restrict__ Whh,
    float* __restrict__ h_state, float* __restrict__ c_state, int TC)
{
    const int tid = threadIdx.x;
    const int blk = blockIdx.x;
    const int j = tid;

    float whh[HH];
#pragma unroll
    for (int q = 0; q < HH / 4; ++q)
        *(float4*)&whh[4 * q] = *(const float4*)&Whh[j * HH + 4 * q];

    __shared__ __align__(16) float h_lds[HH * 4];
    __shared__ __align__(16) float pre_lds[4 * GG];

    const int um = tid >> 7;
    const int uj = tid & 127;
    const long b0 = (long)blk * 4;

    float c = c_state[(b0 + um) * HH + uj];
    h_lds[tid] = h_state[(b0 + (tid & 3)) * HH + (tid >> 2)];

    for (int tt = 0; tt < TC; ++tt) {
        __syncthreads();  // h_lds (init or prev update) visible

        float a0 = xp[((b0 + 0) * TC + tt) * GG + j];
        float a1 = xp[((b0 + 1) * TC + tt) * GG + j];
        float a2 = xp[((b0 + 2) * TC + tt) * GG + j];
        float a3 = xp[((b0 + 3) * TC + tt) * GG + j];
#pragma unroll
        for (int k = 0; k < HH; ++k) {
            float4 v = *(const float4*)&h_lds[k * 4];
            a0 = fmaf(v.x, whh[k], a0);
            a1 = fmaf(v.y, whh[k], a1);
            a2 = fmaf(v.z, whh[k], a2);
            a3 = fmaf(v.w, whh[k], a3);
        }
        pre_lds[0 * GG + j] = a0;
        pre_lds[1 * GG + j] = a1;
        pre_lds[2 * GG + j] = a2;
        pre_lds[3 * GG + j] = a3;
        __syncthreads();

        float pi = pre_lds[um * GG + uj];
        float pf = pre_lds[um * GG + 128 + uj];
        float pg = pre_lds[um * GG + 256 + uj];
        float po = pre_lds[um * GG + 384 + uj];
        float ig = sigmoidf_(pi);
        float fg = sigmoidf_(pf);
        float gg = tanhf_(pg);
        float og = sigmoidf_(po);
        c = fmaf(fg, c, ig * gg);
        float h = og * tanhf_(c);
        h_lds[uj * 4 + um] = h;
    }
    __syncthreads();
    c_state[(b0 + um) * HH + uj] = c;
    h_state[(b0 + (tid & 3)) * HH + (tid >> 2)] = h_lds[tid];
}

// ---------------- FC head: out = relu(h @ fc1^T + b1) @ fc2^T + b2 ---------
__global__ __launch_bounds__(64) void head_kernel(
    const float* __restrict__ h, const float* __restrict__ w1,
    const float* __restrict__ b1, const float* __restrict__ w2,
    const float* __restrict__ b2, float* __restrict__ out)
{
    const int b = blockIdx.x;
    const int n = threadIdx.x;
    float acc = b1[n];
#pragma unroll
    for (int k = 0; k < HH; ++k)
        acc = fmaf(w1[n * HH + k], h[b * HH + k], acc);
    float v = fmaxf(acc, 0.0f) * w2[n];
#pragma unroll
    for (int off = 32; off > 0; off >>= 1)
        v += __shfl_down(v, off);
    if (n == 0) out[b] = v + b2[0];
}

extern "C" void kernel_launch(void* const* d_in, const int* in_sizes, int n_in,
                              void* d_out, int out_size, void* d_ws, size_t ws_size,
                              hipStream_t stream)
{
    const float* x    = (const float*)d_in[0];
    const float* Wih0 = (const float*)d_in[1];
    const float* Whh0 = (const float*)d_in[2];
    const float* bih0 = (const float*)d_in[3];
    const float* bhh0 = (const float*)d_in[4];
    const float* Wih1 = (const float*)d_in[5];
    const float* Whh1 = (const float*)d_in[6];
    const float* bih1 = (const float*)d_in[7];
    const float* bhh1 = (const float*)d_in[8];
    const float* w1   = (const float*)d_in[9];
    const float* b1   = (const float*)d_in[10];
    const float* w2   = (const float*)d_in[11];
    const float* b2   = (const float*)d_in[12];
    float* out = (float*)d_out;

    char* ws = (char*)d_ws;
    const size_t sz_h1 = (size_t)BB * TT * HH * 4;       // 268 MB
    const size_t sz_state = (size_t)BB * HH * 4;         // 512 KB each

    // pick largest T-chunk that fits the workspace
    int TC = 2;
    const int cands[6] = {64, 32, 16, 8, 4, 2};
    for (int i = 0; i < 6; ++i) {
        size_t need = sz_h1 + (size_t)BB * cands[i] * GG * 4 + 2 * sz_state;
        if (need <= ws_size) { TC = cands[i]; break; }
    }

    float* h1 = (float*)(ws);
    float* xp = (float*)(ws + sz_h1);
    float* hs = (float*)(ws + sz_h1 + (size_t)BB * TC * GG * 4);
    float* cs = hs + (size_t)BB * HH;

    hipMemsetAsync(hs, 0, 2 * sz_state, stream);

    lstm0_kernel<<<256, 512, 0, stream>>>(x, Wih0, Whh0, bih0, bhh0, h1);
    for (int t0 = 0; t0 < TT; t0 += TC) {
        xp1_gemm_kernel<<<256, 512, 0, stream>>>(h1, Wih1, bih1, bhh1, xp, t0, TC);
        lstm1_kernel<<<256, 512, 0, stream>>>(xp, Whh1, hs, cs, TC);
    }
    head_kernel<<<BB, 64, 0, stream>>>(hs, w1, b1, w2, b2, out);
}